// Round 15
// baseline (185.769 us; speedup 1.0000x reference)
//
#include <hip/hip_runtime.h>

#define NN 50000
#define NE 1600000
#define D 64
#define NR 6
#define NSEG (NN * NR)          // 300000
#define SB 512
#define SNB ((NSEG + SB - 1) / SB)   // 586
#define BFRAG_N (4 * 14 * 64 * 8)    // 28672
#define NTH4 (NE / 4)           // 400000 (== NN*D/8)
#define NTH8 (NE / 8)           // 200000

typedef __attribute__((ext_vector_type(8))) short short8;
typedef __attribute__((ext_vector_type(4))) float f32x4;

__device__ __forceinline__ unsigned short f2bf(float f) {
    unsigned int u = __float_as_uint(f);
    unsigned int r = (u + 0x7FFF + ((u >> 16) & 1)) >> 16;   // RNE
    return (unsigned short)r;
}

// fused: 4-edge atomic ranking + x->bf16 (8 elems/thread) + Bfrag build.
// cnt must be zeroed beforehand (hipMemsetAsync).
__global__ void count_prep_k(const float* __restrict__ x, const float* __restrict__ W,
                             const float* __restrict__ root,
                             const int* __restrict__ dsts, const int* __restrict__ et,
                             int* __restrict__ cnt, int* __restrict__ rank,
                             unsigned short* __restrict__ xh,
                             unsigned short* __restrict__ Bfrag) {
    int t = blockIdx.x * blockDim.x + threadIdx.x;
    if (t >= NTH4) return;
    // issue the 4 independent atomics first (latency shadow covers the rest)
    int e0 = t, e1 = t + NTH4, e2 = t + 2 * NTH4, e3 = t + 3 * NTH4;
    int s0 = dsts[e0] * NR + et[e0];
    int s1 = dsts[e1] * NR + et[e1];
    int s2 = dsts[e2] * NR + et[e2];
    int s3 = dsts[e3] * NR + et[e3];
    int r0 = atomicAdd(&cnt[s0], 1);
    int r1 = atomicAdd(&cnt[s1], 1);
    int r2 = atomicAdd(&cnt[s2], 1);
    int r3 = atomicAdd(&cnt[s3], 1);
    // xh: 8 consecutive bf16 per thread (NN*D/8 == NTH4 exactly)
    {
        const float4* xp = (const float4*)(x + (size_t)t * 8);
        float4 va = xp[0], vb = xp[1];
        uint4 o;
        o.x = (unsigned int)f2bf(va.x) | ((unsigned int)f2bf(va.y) << 16);
        o.y = (unsigned int)f2bf(va.z) | ((unsigned int)f2bf(va.w) << 16);
        o.z = (unsigned int)f2bf(vb.x) | ((unsigned int)f2bf(vb.y) << 16);
        o.w = (unsigned int)f2bf(vb.z) | ((unsigned int)f2bf(vb.w) << 16);
        *(uint4*)(xh + (size_t)t * 8) = o;
    }
    if (t < BFRAG_N) {
        int j = t & 7;
        int lane = (t >> 3) & 63;
        int rest = t >> 9;
        int ks = rest % 14;
        int nt = rest / 14;
        int k = ks * 32 + ((lane >> 4) * 8) + j;
        int n = nt * 16 + (lane & 15);
        float v = (k < 384) ? W[(size_t)k * 64 + n] : root[(size_t)(k - 384) * 64 + n];
        Bfrag[t] = f2bf(v);
    }
    rank[e0] = r0;
    rank[e1] = r1;
    rank[e2] = r2;
    rank[e3] = r3;
}

// ---- two-level exclusive scan over cnt[NSEG] -> rowstart[NSEG+1] ----
__global__ void scanA_k(const int* __restrict__ cnt, int* __restrict__ incl,
                        int* __restrict__ blocksum) {
    __shared__ int s[SB];
    int t = threadIdx.x, i = blockIdx.x * SB + t;
    s[t] = (i < NSEG) ? cnt[i] : 0;
    __syncthreads();
    for (int off = 1; off < SB; off <<= 1) {
        int u = (t >= off) ? s[t - off] : 0;
        __syncthreads();
        s[t] += u;
        __syncthreads();
    }
    if (i < NSEG) incl[i] = s[t];
    if (t == SB - 1) blocksum[blockIdx.x] = s[t];
}

__global__ void scanB_k(const int* __restrict__ blocksum, int* __restrict__ blockoff) {
    __shared__ int s[1024];
    int t = threadIdx.x;
    s[t] = (t < SNB) ? blocksum[t] : 0;
    __syncthreads();
    for (int off = 1; off < 1024; off <<= 1) {
        int u = (t >= off) ? s[t - off] : 0;
        __syncthreads();
        s[t] += u;
        __syncthreads();
    }
    if (t < SNB) blockoff[t] = s[t];
}

__global__ void scanC_k(const int* __restrict__ incl, const int* __restrict__ blockoff,
                        int* __restrict__ rowstart) {
    int i = blockIdx.x * blockDim.x + threadIdx.x;
    if (i >= NSEG) return;
    int b = i / SB;
    int Ri = incl[i] + (b > 0 ? blockoff[b - 1] : 0);
    rowstart[i + 1] = Ri;
    if (i == 0) rowstart[0] = 0;
}

// placement: no atomics; pos = rowstart[seg] + rank[e]; 8 edges/thread.
// pay holds PRE-SHIFTED byte offsets (src*128) for agg's gather.
__global__ void place_k(const int* __restrict__ srcs, const int* __restrict__ dsts,
                        const int* __restrict__ et, const int* __restrict__ rowstart,
                        const int* __restrict__ rank, int* __restrict__ pay) {
    int t = blockIdx.x * blockDim.x + threadIdx.x;
    if (t >= NTH8) return;
#pragma unroll
    for (int j = 0; j < 8; ++j) {
        int e = t + j * NTH8;
        int seg = dsts[e] * NR + et[e];
        pay[rowstart[seg] + rank[e]] = srcs[e] << 7;
    }
}

// Two segments per wave: lane group g=lane>>5 owns segment 2*wave+g;
// cp=lane&31 owns channels {2cp,2cp+1}. No shfl, no division.
// Amain offset = seg*64 (seg-major = [n][r*64+d] for KTOT=384).
__global__ __launch_bounds__(256) void agg8_k(const unsigned short* __restrict__ xh,
                                              const int* __restrict__ rowstart,
                                              const int* __restrict__ pay,
                                              unsigned short* __restrict__ Amain) {
    int wv = (blockIdx.x * blockDim.x + threadIdx.x) >> 6;
    int lane = threadIdx.x & 63;
    int g = lane >> 5;
    int cp = lane & 31;
    int seg = 2 * wv + g;
    if (seg >= NSEG) return;
    int k0 = rowstart[seg], k1 = rowstart[seg + 1];
    const char* xb = (const char*)xh;
    unsigned int cpo = (unsigned int)cp << 2;               // byte offset within row
    float ax = 0.f, ay = 0.f;
    for (int k = k0; k < k1; k += 4) {
        unsigned int pv[4];
        float mv[4];
#pragma unroll
        for (int j = 0; j < 4; ++j) {
            int kk = k + j;
            bool v = kk < k1;
            mv[j] = v ? 1.0f : 0.0f;
            pv[j] = (unsigned int)pay[v ? kk : k];
        }
#pragma unroll
        for (int j = 0; j < 4; ++j) {
            unsigned int u = *(const unsigned int*)(xb + pv[j] + cpo);
            ax += __uint_as_float(u << 16) * mv[j];          // channel 2cp
            ay += __uint_as_float(u & 0xFFFF0000u) * mv[j];  // channel 2cp+1
        }
    }
    int c = k1 - k0;
    float nrm = (c > 0) ? 1.0f / (float)c : 0.0f;
    unsigned int o = (unsigned int)f2bf(ax * nrm) | ((unsigned int)f2bf(ay * nrm) << 16);
    *(unsigned int*)(Amain + (size_t)seg * 64 + 2 * cp) = o;
}

// MFMA GEMM: out = bias + A @ B; M=NN, K=448, N=64. K slots 0-383 from Amain,
// 384-447 (root term) straight from xh. 4 waves/block, 16-row strips.
__global__ __launch_bounds__(256) void mix4_k(const unsigned short* __restrict__ Amain,
                                              const unsigned short* __restrict__ xh,
                                              const unsigned short* __restrict__ Bfrag,
                                              const float* __restrict__ bias,
                                              float* __restrict__ out) {
    int t = threadIdx.x;
    int lane = t & 63;
    int w = t >> 6;
    int rowb = blockIdx.x * 64 + w * 16;
    int arow = rowb + (lane & 15);
    if (arow >= NN) arow = NN - 1;
    int ko = (lane >> 4) * 8;
    const unsigned short* ap = Amain + (size_t)arow * 384 + ko;
    const unsigned short* xp = xh + (size_t)arow * 64 + ko;
    const short8* bp = (const short8*)Bfrag + lane;
    f32x4 acc0 = {0.f, 0.f, 0.f, 0.f};
    f32x4 acc1 = acc0, acc2 = acc0, acc3 = acc0;
#pragma unroll
    for (int ks = 0; ks < 14; ++ks) {
        short8 a = (ks < 12) ? *(const short8*)(ap + ks * 32)
                             : *(const short8*)(xp + (ks - 12) * 32);
        short8 b0 = bp[(0 * 14 + ks) * 64];
        short8 b1 = bp[(1 * 14 + ks) * 64];
        short8 b2 = bp[(2 * 14 + ks) * 64];
        short8 b3 = bp[(3 * 14 + ks) * 64];
        acc0 = __builtin_amdgcn_mfma_f32_16x16x32_bf16(a, b0, acc0, 0, 0, 0);
        acc1 = __builtin_amdgcn_mfma_f32_16x16x32_bf16(a, b1, acc1, 0, 0, 0);
        acc2 = __builtin_amdgcn_mfma_f32_16x16x32_bf16(a, b2, acc2, 0, 0, 0);
        acc3 = __builtin_amdgcn_mfma_f32_16x16x32_bf16(a, b3, acc3, 0, 0, 0);
    }
    int col = lane & 15;
    int rout = rowb + (lane >> 4) * 4;
    float bv0 = bias[0 * 16 + col];
    float bv1 = bias[1 * 16 + col];
    float bv2 = bias[2 * 16 + col];
    float bv3 = bias[3 * 16 + col];
#pragma unroll
    for (int j = 0; j < 4; ++j) {
        int rr = rout + j;
        if (rr < NN) {
            float* op = out + (size_t)rr * 64;
            op[0 * 16 + col] = acc0[j] + bv0;
            op[1 * 16 + col] = acc1[j] + bv1;
            op[2 * 16 + col] = acc2[j] + bv2;
            op[3 * 16 + col] = acc3[j] + bv3;
        }
    }
}

// ---------- fallback path (small ws) ----------
__global__ void zero_i32_k(int* __restrict__ p, int n) {
    int i = blockIdx.x * blockDim.x + threadIdx.x;
    if (i < n) p[i] = 0;
}

__global__ void count_edges_k(const int* __restrict__ dst, const int* __restrict__ et,
                              int* __restrict__ cnt) {
    int e = blockIdx.x * blockDim.x + threadIdx.x;
    if (e < NE) atomicAdd(&cnt[dst[e] * NR + et[e]], 1);
}

__global__ void make_norm_k(const int* __restrict__ cnt, float* __restrict__ norm, int n) {
    int i = blockIdx.x * blockDim.x + threadIdx.x;
    if (i < n) {
        int c = cnt[i];
        norm[i] = (c > 0) ? 1.0f / (float)c : 0.0f;
    }
}

__global__ void init_out_k(const float* __restrict__ x, const float* __restrict__ root,
                           const float* __restrict__ bias, float* __restrict__ out) {
    int t = blockIdx.x * blockDim.x + threadIdx.x;
    int n = t >> 6;
    int o = t & 63;
    if (n >= NN) return;
    const float* xrow = x + n * D;
    float acc = bias[o];
#pragma unroll
    for (int d = 0; d < D; ++d) acc = fmaf(xrow[d], root[d * D + o], acc);
    out[t] = acc;
}

__global__ void scatter_mv_k(const int* __restrict__ srcs, const int* __restrict__ dsts,
                             const int* __restrict__ et, const float* __restrict__ x,
                             const float* __restrict__ W, const float* __restrict__ norm,
                             float* __restrict__ out) {
    int t = blockIdx.x * blockDim.x + threadIdx.x;
    int e = t >> 6;
    int o = t & 63;
    if (e >= NE) return;
    int s = srcs[e];
    int d2 = dsts[e];
    int r = et[e];
    float nrm = norm[d2 * NR + r];
    const float* xrow = x + s * D;
    const float* Wr = W + r * D * D + o;
    float acc = 0.0f;
#pragma unroll
    for (int d = 0; d < D; ++d) acc = fmaf(xrow[d], Wr[d * D], acc);
    atomicAdd(&out[d2 * D + o], acc * nrm);
}

extern "C" void kernel_launch(void* const* d_in, const int* in_sizes, int n_in,
                              void* d_out, int out_size, void* d_ws, size_t ws_size,
                              hipStream_t stream) {
    const float* x    = (const float*)d_in[0];
    const float* W    = (const float*)d_in[1];
    const float* root = (const float*)d_in[2];
    const float* bias = (const float*)d_in[3];
    const int*   ei   = (const int*)d_in[4];
    const int*   et   = (const int*)d_in[5];
    float* out = (float*)d_out;
    const int* srcs = ei;
    const int* dsts = ei + NE;

    // fully disjoint workspace layout (~64 MB)
    char* ws = (char*)d_ws;
    size_t off = 0;
    int*   rowstart = (int*)(ws + off); off += (size_t)(NSEG + 1) * 4;
    int*   pay      = (int*)(ws + off); off += (size_t)NE * 4;
    int*   rank     = (int*)(ws + off); off += (size_t)NE * 4;
    off = (off + 255) & ~(size_t)255;
    unsigned short* Bfrag = (unsigned short*)(ws + off); off += (size_t)BFRAG_N * 2;
    off = (off + 255) & ~(size_t)255;
    unsigned short* xh = (unsigned short*)(ws + off); off += (size_t)NN * D * 2;
    off = (off + 255) & ~(size_t)255;
    int* cnt      = (int*)(ws + off); off += (size_t)NSEG * 4;
    int* incl     = (int*)(ws + off); off += (size_t)NSEG * 4;
    int* blocksum = (int*)(ws + off); off += (size_t)SNB * 4;
    int* blockoff = (int*)(ws + off); off += (size_t)SNB * 4;
    off = (off + 255) & ~(size_t)255;
    unsigned short* Amain = (unsigned short*)(ws + off); off += (size_t)NN * 384 * 2;  // 38.4 MB
    bool big = ws_size >= off;

    if (big) {
        hipMemsetAsync(cnt, 0, (size_t)NSEG * 4, stream);
        count_prep_k<<<(NTH4 + 255) / 256, 256, 0, stream>>>(x, W, root, dsts, et,
                                                             cnt, rank, xh, Bfrag);
        scanA_k<<<SNB, SB, 0, stream>>>(cnt, incl, blocksum);
        scanB_k<<<1, 1024, 0, stream>>>(blocksum, blockoff);
        scanC_k<<<(NSEG + 255) / 256, 256, 0, stream>>>(incl, blockoff, rowstart);
        place_k<<<(NTH8 + 255) / 256, 256, 0, stream>>>(srcs, dsts, et, rowstart, rank, pay);
        int aggwaves = NSEG / 2;                      // 150000
        agg8_k<<<((size_t)aggwaves * 64 + 255) / 256, 256, 0, stream>>>(xh, rowstart, pay, Amain);
        mix4_k<<<(NN + 63) / 64, 256, 0, stream>>>(Amain, xh, Bfrag, bias, out);
    } else {
        int* cnt2  = (int*)(ws);
        float* norm = (float*)(ws + (size_t)NSEG * 4);
        zero_i32_k<<<(NSEG + 255) / 256, 256, 0, stream>>>(cnt2, NSEG);
        count_edges_k<<<(NE + 255) / 256, 256, 0, stream>>>(dsts, et, cnt2);
        make_norm_k<<<(NSEG + 255) / 256, 256, 0, stream>>>(cnt2, norm, NSEG);
        init_out_k<<<((size_t)NN * 64 + 255) / 256, 256, 0, stream>>>(x, root, bias, out);
        scatter_mv_k<<<((size_t)NE * 64 + 255) / 256, 256, 0, stream>>>(srcs, dsts, et, x, W, norm, out);
    }
}

// Round 16
// 125.870 us; speedup vs baseline: 1.4759x; 1.4759x over previous
//
#include <hip/hip_runtime.h>

#define NN 50000
#define NE 1600000
#define D 64
#define NR 6
#define NSEG (NN * NR)          // 300000
#define SB 512
#define BFRAG_N (4 * 14 * 64 * 8)    // 28672
#define EPB 6400                // edges per pass-1 block
#define NBLK1 (NE / EPB)        // 250 (exact)
#define NBUK ((NSEG + 1023) >> 10)   // 293
#define NG (NBUK * NBLK1)       // 73250
#define SNB1 ((NG + SB - 1) / SB)    // 144

typedef __attribute__((ext_vector_type(8))) short short8;
typedef __attribute__((ext_vector_type(4))) float f32x4;

__device__ __forceinline__ unsigned short f2bf(float f) {
    unsigned int u = __float_as_uint(f);
    unsigned int r = (u + 0x7FFF + ((u >> 16) & 1)) >> 16;   // RNE
    return (unsigned short)r;
}

// xh (bf16 copy of x) + Bfrag build; no atomics, no cnt
__global__ void prep_k(const float* __restrict__ x, const float* __restrict__ W,
                       const float* __restrict__ root,
                       unsigned short* __restrict__ xh, unsigned short* __restrict__ Bfrag) {
    int t = blockIdx.x * blockDim.x + threadIdx.x;
    if (t < NN * D / 8) {
        const float4* xp = (const float4*)(x + (size_t)t * 8);
        float4 va = xp[0], vb = xp[1];
        uint4 o;
        o.x = (unsigned int)f2bf(va.x) | ((unsigned int)f2bf(va.y) << 16);
        o.y = (unsigned int)f2bf(va.z) | ((unsigned int)f2bf(va.w) << 16);
        o.z = (unsigned int)f2bf(vb.x) | ((unsigned int)f2bf(vb.y) << 16);
        o.w = (unsigned int)f2bf(vb.z) | ((unsigned int)f2bf(vb.w) << 16);
        *(uint4*)(xh + (size_t)t * 8) = o;
    }
    if (t < BFRAG_N) {
        int j = t & 7;
        int lane = (t >> 3) & 63;
        int rest = t >> 9;
        int ks = rest % 14;
        int nt = rest / 14;
        int k = ks * 32 + ((lane >> 4) * 8) + j;
        int n = nt * 16 + (lane & 15);
        float v = (k < 384) ? W[(size_t)k * 64 + n] : root[(size_t)(k - 384) * 64 + n];
        Bfrag[t] = f2bf(v);
    }
}

// pass 1a: per-block bucket histogram (bucket = seg>>10), LDS atomics only
__global__ __launch_bounds__(256) void hist1_k(const int* __restrict__ dsts,
                                               const int* __restrict__ et,
                                               int* __restrict__ ghist) {
    __shared__ int lh[NBUK];
    int tid = threadIdx.x, blk = blockIdx.x;
    for (int i = tid; i < NBUK; i += 256) lh[i] = 0;
    __syncthreads();
    int base = blk * EPB;
#pragma unroll 5
    for (int i = 0; i < EPB / 256; ++i) {
        int e = base + i * 256 + tid;
        int seg = dsts[e] * NR + et[e];
        atomicAdd(&lh[seg >> 10], 1);
    }
    __syncthreads();
    for (int i = tid; i < NBUK; i += 256) ghist[i * NBLK1 + blk] = lh[i];
}

// ---- scan over ghist[NG] (bucket-major) -> exclusive goff[NG] ----
__global__ void scanA_k(const int* __restrict__ v, int* __restrict__ incl,
                        int* __restrict__ blocksum, int n) {
    __shared__ int s[SB];
    int t = threadIdx.x, i = blockIdx.x * SB + t;
    s[t] = (i < n) ? v[i] : 0;
    __syncthreads();
    for (int off = 1; off < SB; off <<= 1) {
        int u = (t >= off) ? s[t - off] : 0;
        __syncthreads();
        s[t] += u;
        __syncthreads();
    }
    if (i < n) incl[i] = s[t];
    if (t == SB - 1) blocksum[blockIdx.x] = s[t];
}

__global__ void scanB_k(const int* __restrict__ blocksum, int* __restrict__ blockoff, int nb) {
    __shared__ int s[1024];
    int t = threadIdx.x;
    s[t] = (t < nb) ? blocksum[t] : 0;
    __syncthreads();
    for (int off = 1; off < 1024; off <<= 1) {
        int u = (t >= off) ? s[t - off] : 0;
        __syncthreads();
        s[t] += u;
        __syncthreads();
    }
    if (t < nb) blockoff[t] = s[t];
}

__global__ void scanC2_k(const int* __restrict__ incl, const int* __restrict__ blockoff,
                         const int* __restrict__ v, int* __restrict__ excl, int n) {
    int i = blockIdx.x * blockDim.x + threadIdx.x;
    if (i >= n) return;
    int b = i / SB;
    int Ri = incl[i] + (b > 0 ? blockoff[b - 1] : 0);
    excl[i] = Ri - v[i];
}

// pass 1b: scatter edges into bucket-grouped kv = (src<<7, seg); LDS cursors
__global__ __launch_bounds__(256) void scatter1_k(const int* __restrict__ srcs,
                                                  const int* __restrict__ dsts,
                                                  const int* __restrict__ et,
                                                  const int* __restrict__ goff,
                                                  uint2* __restrict__ kv) {
    __shared__ int cur[NBUK];
    int tid = threadIdx.x, blk = blockIdx.x;
    for (int i = tid; i < NBUK; i += 256) cur[i] = goff[i * NBLK1 + blk];
    __syncthreads();
    int base = blk * EPB;
#pragma unroll 5
    for (int i = 0; i < EPB / 256; ++i) {
        int e = base + i * 256 + tid;
        int seg = dsts[e] * NR + et[e];
        int pos = atomicAdd(&cur[seg >> 10], 1);
        kv[pos] = make_uint2((unsigned int)srcs[e] << 7, (unsigned int)seg);
    }
}

// pass 2: one block per bucket; LDS histogram over 1024 segments -> rowstart + pay
__global__ __launch_bounds__(256) void bucket2_k(const uint2* __restrict__ kv,
                                                 const int* __restrict__ goff,
                                                 int* __restrict__ rowstart,
                                                 int* __restrict__ pay) {
    __shared__ int h[1024];
    __shared__ int part[256];
    int tid = threadIdx.x, b = blockIdx.x;
    int base = goff[b * NBLK1];
    int end  = (b + 1 < NBUK) ? goff[(b + 1) * NBLK1] : NE;
    for (int i = tid; i < 1024; i += 256) h[i] = 0;
    __syncthreads();
    for (int k = base + tid; k < end; k += 256)
        atomicAdd(&h[kv[k].y & 1023], 1);
    __syncthreads();
    int c0 = h[4 * tid], c1 = h[4 * tid + 1], c2 = h[4 * tid + 2], c3 = h[4 * tid + 3];
    part[tid] = c0 + c1 + c2 + c3;
    __syncthreads();
    for (int off = 1; off < 256; off <<= 1) {
        int u = (tid >= off) ? part[tid - off] : 0;
        __syncthreads();
        part[tid] += u;
        __syncthreads();
    }
    int pbase = (tid > 0) ? part[tid - 1] : 0;   // exclusive across thread groups
    __syncthreads();
    int e0 = pbase, e1 = pbase + c0, e2 = pbase + c0 + c1, e3 = pbase + c0 + c1 + c2;
    h[4 * tid] = e0; h[4 * tid + 1] = e1; h[4 * tid + 2] = e2; h[4 * tid + 3] = e3;
    int segb = b << 10;
    if (segb + 4 * tid     < NSEG) rowstart[segb + 4 * tid]     = base + e0;
    if (segb + 4 * tid + 1 < NSEG) rowstart[segb + 4 * tid + 1] = base + e1;
    if (segb + 4 * tid + 2 < NSEG) rowstart[segb + 4 * tid + 2] = base + e2;
    if (segb + 4 * tid + 3 < NSEG) rowstart[segb + 4 * tid + 3] = base + e3;
    if (b == 0 && tid == 0) rowstart[NSEG] = NE;
    __syncthreads();
    for (int k = base + tid; k < end; k += 256) {
        uint2 v = kv[k];
        int pos = base + atomicAdd(&h[v.y & 1023], 1);
        pay[pos] = (int)v.x;
    }
}

// Two segments per wave (unchanged from round 14/15)
__global__ __launch_bounds__(256) void agg8_k(const unsigned short* __restrict__ xh,
                                              const int* __restrict__ rowstart,
                                              const int* __restrict__ pay,
                                              unsigned short* __restrict__ Amain) {
    int wv = (blockIdx.x * blockDim.x + threadIdx.x) >> 6;
    int lane = threadIdx.x & 63;
    int g = lane >> 5;
    int cp = lane & 31;
    int seg = 2 * wv + g;
    if (seg >= NSEG) return;
    int k0 = rowstart[seg], k1 = rowstart[seg + 1];
    const char* xb = (const char*)xh;
    unsigned int cpo = (unsigned int)cp << 2;
    float ax = 0.f, ay = 0.f;
    for (int k = k0; k < k1; k += 4) {
        unsigned int pv[4];
        float mv[4];
#pragma unroll
        for (int j = 0; j < 4; ++j) {
            int kk = k + j;
            bool v = kk < k1;
            mv[j] = v ? 1.0f : 0.0f;
            pv[j] = (unsigned int)pay[v ? kk : k];
        }
#pragma unroll
        for (int j = 0; j < 4; ++j) {
            unsigned int u = *(const unsigned int*)(xb + pv[j] + cpo);
            ax += __uint_as_float(u << 16) * mv[j];
            ay += __uint_as_float(u & 0xFFFF0000u) * mv[j];
        }
    }
    int c = k1 - k0;
    float nrm = (c > 0) ? 1.0f / (float)c : 0.0f;
    unsigned int o = (unsigned int)f2bf(ax * nrm) | ((unsigned int)f2bf(ay * nrm) << 16);
    *(unsigned int*)(Amain + (size_t)seg * 64 + 2 * cp) = o;
}

// MFMA GEMM (unchanged from round 14/15)
__global__ __launch_bounds__(256) void mix4_k(const unsigned short* __restrict__ Amain,
                                              const unsigned short* __restrict__ xh,
                                              const unsigned short* __restrict__ Bfrag,
                                              const float* __restrict__ bias,
                                              float* __restrict__ out) {
    int t = threadIdx.x;
    int lane = t & 63;
    int w = t >> 6;
    int rowb = blockIdx.x * 64 + w * 16;
    int arow = rowb + (lane & 15);
    if (arow >= NN) arow = NN - 1;
    int ko = (lane >> 4) * 8;
    const unsigned short* ap = Amain + (size_t)arow * 384 + ko;
    const unsigned short* xp = xh + (size_t)arow * 64 + ko;
    const short8* bp = (const short8*)Bfrag + lane;
    f32x4 acc0 = {0.f, 0.f, 0.f, 0.f};
    f32x4 acc1 = acc0, acc2 = acc0, acc3 = acc0;
#pragma unroll
    for (int ks = 0; ks < 14; ++ks) {
        short8 a = (ks < 12) ? *(const short8*)(ap + ks * 32)
                             : *(const short8*)(xp + (ks - 12) * 32);
        short8 b0 = bp[(0 * 14 + ks) * 64];
        short8 b1 = bp[(1 * 14 + ks) * 64];
        short8 b2 = bp[(2 * 14 + ks) * 64];
        short8 b3 = bp[(3 * 14 + ks) * 64];
        acc0 = __builtin_amdgcn_mfma_f32_16x16x32_bf16(a, b0, acc0, 0, 0, 0);
        acc1 = __builtin_amdgcn_mfma_f32_16x16x32_bf16(a, b1, acc1, 0, 0, 0);
        acc2 = __builtin_amdgcn_mfma_f32_16x16x32_bf16(a, b2, acc2, 0, 0, 0);
        acc3 = __builtin_amdgcn_mfma_f32_16x16x32_bf16(a, b3, acc3, 0, 0, 0);
    }
    int col = lane & 15;
    int rout = rowb + (lane >> 4) * 4;
    float bv0 = bias[0 * 16 + col];
    float bv1 = bias[1 * 16 + col];
    float bv2 = bias[2 * 16 + col];
    float bv3 = bias[3 * 16 + col];
#pragma unroll
    for (int j = 0; j < 4; ++j) {
        int rr = rout + j;
        if (rr < NN) {
            float* op = out + (size_t)rr * 64;
            op[0 * 16 + col] = acc0[j] + bv0;
            op[1 * 16 + col] = acc1[j] + bv1;
            op[2 * 16 + col] = acc2[j] + bv2;
            op[3 * 16 + col] = acc3[j] + bv3;
        }
    }
}

// ---------- fallback path (small ws) ----------
__global__ void zero_i32_k(int* __restrict__ p, int n) {
    int i = blockIdx.x * blockDim.x + threadIdx.x;
    if (i < n) p[i] = 0;
}

__global__ void count_edges_k(const int* __restrict__ dst, const int* __restrict__ et,
                              int* __restrict__ cnt) {
    int e = blockIdx.x * blockDim.x + threadIdx.x;
    if (e < NE) atomicAdd(&cnt[dst[e] * NR + et[e]], 1);
}

__global__ void make_norm_k(const int* __restrict__ cnt, float* __restrict__ norm, int n) {
    int i = blockIdx.x * blockDim.x + threadIdx.x;
    if (i < n) {
        int c = cnt[i];
        norm[i] = (c > 0) ? 1.0f / (float)c : 0.0f;
    }
}

__global__ void init_out_k(const float* __restrict__ x, const float* __restrict__ root,
                           const float* __restrict__ bias, float* __restrict__ out) {
    int t = blockIdx.x * blockDim.x + threadIdx.x;
    int n = t >> 6;
    int o = t & 63;
    if (n >= NN) return;
    const float* xrow = x + n * D;
    float acc = bias[o];
#pragma unroll
    for (int d = 0; d < D; ++d) acc = fmaf(xrow[d], root[d * D + o], acc);
    out[t] = acc;
}

__global__ void scatter_mv_k(const int* __restrict__ srcs, const int* __restrict__ dsts,
                             const int* __restrict__ et, const float* __restrict__ x,
                             const float* __restrict__ W, const float* __restrict__ norm,
                             float* __restrict__ out) {
    int t = blockIdx.x * blockDim.x + threadIdx.x;
    int e = t >> 6;
    int o = t & 63;
    if (e >= NE) return;
    int s = srcs[e];
    int d2 = dsts[e];
    int r = et[e];
    float nrm = norm[d2 * NR + r];
    const float* xrow = x + s * D;
    const float* Wr = W + r * D * D + o;
    float acc = 0.0f;
#pragma unroll
    for (int d = 0; d < D; ++d) acc = fmaf(xrow[d], Wr[d * D], acc);
    atomicAdd(&out[d2 * D + o], acc * nrm);
}

extern "C" void kernel_launch(void* const* d_in, const int* in_sizes, int n_in,
                              void* d_out, int out_size, void* d_ws, size_t ws_size,
                              hipStream_t stream) {
    const float* x    = (const float*)d_in[0];
    const float* W    = (const float*)d_in[1];
    const float* root = (const float*)d_in[2];
    const float* bias = (const float*)d_in[3];
    const int*   ei   = (const int*)d_in[4];
    const int*   et   = (const int*)d_in[5];
    float* out = (float*)d_out;
    const int* srcs = ei;
    const int* dsts = ei + NE;

    // workspace layout (~67 MB)
    char* ws = (char*)d_ws;
    size_t off = 0;
    int*   rowstart = (int*)(ws + off); off += (size_t)(NSEG + 1) * 4;
    int*   pay      = (int*)(ws + off); off += (size_t)NE * 4;
    off = (off + 255) & ~(size_t)255;
    uint2* kv       = (uint2*)(ws + off); off += (size_t)NE * 8;
    int*   ghist    = (int*)(ws + off); off += (size_t)NG * 4;
    int*   incl     = (int*)(ws + off); off += (size_t)NG * 4;
    int*   goff     = (int*)(ws + off); off += (size_t)NG * 4;
    int*   blocksum = (int*)(ws + off); off += (size_t)SNB1 * 4;
    int*   blockoff = (int*)(ws + off); off += (size_t)SNB1 * 4;
    off = (off + 255) & ~(size_t)255;
    unsigned short* Bfrag = (unsigned short*)(ws + off); off += (size_t)BFRAG_N * 2;
    off = (off + 255) & ~(size_t)255;
    unsigned short* xh = (unsigned short*)(ws + off); off += (size_t)NN * D * 2;
    off = (off + 255) & ~(size_t)255;
    unsigned short* Amain = (unsigned short*)(ws + off); off += (size_t)NN * 384 * 2;
    bool big = ws_size >= off;

    if (big) {
        prep_k<<<(NN * D / 8 + 255) / 256, 256, 0, stream>>>(x, W, root, xh, Bfrag);
        hist1_k<<<NBLK1, 256, 0, stream>>>(dsts, et, ghist);
        scanA_k<<<SNB1, SB, 0, stream>>>(ghist, incl, blocksum, NG);
        scanB_k<<<1, 1024, 0, stream>>>(blocksum, blockoff, SNB1);
        scanC2_k<<<(NG + 255) / 256, 256, 0, stream>>>(incl, blockoff, ghist, goff, NG);
        scatter1_k<<<NBLK1, 256, 0, stream>>>(srcs, dsts, et, goff, kv);
        bucket2_k<<<NBUK, 256, 0, stream>>>(kv, goff, rowstart, pay);
        int aggwaves = NSEG / 2;
        agg8_k<<<((size_t)aggwaves * 64 + 255) / 256, 256, 0, stream>>>(xh, rowstart, pay, Amain);
        mix4_k<<<(NN + 63) / 64, 256, 0, stream>>>(Amain, xh, Bfrag, bias, out);
    } else {
        int* cnt2  = (int*)(ws);
        float* norm = (float*)(ws + (size_t)NSEG * 4);
        zero_i32_k<<<(NSEG + 255) / 256, 256, 0, stream>>>(cnt2, NSEG);
        count_edges_k<<<(NE + 255) / 256, 256, 0, stream>>>(dsts, et, cnt2);
        make_norm_k<<<(NSEG + 255) / 256, 256, 0, stream>>>(cnt2, norm, NSEG);
        init_out_k<<<((size_t)NN * 64 + 255) / 256, 256, 0, stream>>>(x, root, bias, out);
        scatter_mv_k<<<((size_t)NE * 64 + 255) / 256, 256, 0, stream>>>(srcs, dsts, et, x, W, norm, out);
    }
}